// Round 4
// baseline (164.644 us; speedup 1.0000x reference)
//
#include <hip/hip_runtime.h>
#include <hip/hip_bf16.h>

#define NB 32768      // batch rows per node
#define CD 128        // input channels
#define NNODES 6
#define OUTW 1536     // 6*256 output cols
#define KW 256        // concat K per node GEMM

typedef __attribute__((ext_vector_type(8))) short short8;
typedef __attribute__((ext_vector_type(4))) float f32x4;

// hardware f32->bf16 (RNE)
static __device__ __forceinline__ short f2bf(float f) {
    union { __bf16 b; short s; } u;
    u.b = (__bf16)f;
    return u.s;
}

// ---- prologue: Wcat[o][k] bf16 in d_ws; k<128 -> Wl[o][k], else Wr[o][k-128]
__global__ void prep_w(const float* __restrict__ Wl, const float* __restrict__ Wr,
                       short* __restrict__ Wb) {
    const int i = (blockIdx.x * 256 + threadIdx.x) * 8;   // short8 chunk
    const int o = i >> 8;
    const int k = i & 255;
    const float* src = (k < 128) ? (Wl + o * CD + k) : (Wr + o * CD + (k - 128));
    f32x4 a = *(const f32x4*)src;
    f32x4 b = *(const f32x4*)(src + 4);
    short8 p;
    #pragma unroll
    for (int j = 0; j < 4; ++j) { p[j] = f2bf(a[j]); p[4 + j] = f2bf(b[j]); }
    *(short8*)(Wb + i) = p;
}

// LDS-free fused SAGE. Wave = 16 rows x 32 cols (2 strips) x 6 nodes ->
// acc[6][2] (48 f32) so total regs fit 3 waves/SIMD (R3 was 2: 96-f32 acc).
// MFMA operands SWAPPED vs R3: mfma(Wfrag, datafrag, acc) -> D row = out
// channel, D col = batch row -> each lane's f32x4 acc = 4 consecutive out
// floats -> dwordx4 stores.
__global__ __launch_bounds__(256, 3)
void sage_v4(const float* __restrict__ x, const short* __restrict__ Wb,
             const float* __restrict__ bias, float* __restrict__ out) {
    const int t = threadIdx.x;
    const int lane = t & 63;
    const int wv = t >> 6;        // 0..3
    const int lo = lane & 15;     // batch row within group (A... now B col / D col)
    const int hi = lane >> 4;     // k-subchunk / D-row-group

    // XCD-pair swizzle: blocks b and b^8 share a row-group and (round-robin
    // dispatch by b%8) land on the same XCD -> second block L2-hits x.
    const int b = blockIdx.x;
    const int half = (b >> 3) & 1;                 // which 128-col half
    const int rowGroup = (b >> 4) * 8 + (b & 7);   // 0..2047, bijective
    const int obase = half * 128 + wv * 32;
    const size_t row = (size_t)rowGroup * 16 + lo;

    f32x4 bias_v[2];
    #pragma unroll
    for (int i = 0; i < 2; ++i)
        bias_v[i] = *(const f32x4*)&bias[obase + i * 16 + hi * 4];

    f32x4 acc[NNODES][2];
    #pragma unroll
    for (int n = 0; n < NNODES; ++n)
        #pragma unroll
        for (int i = 0; i < 2; ++i) acc[n][i] = (f32x4){0.f, 0.f, 0.f, 0.f};

    #pragma unroll
    for (int m = 0; m < 4; ++m) {                  // 32-channel chunk
        const float* pb = x + row * CD + m * 32 + hi * 8;
        float x0[8], x1[8], S01[8], S25[8], S34[8];
        short8 xb[NNODES];
        {   // node 0,1 kept in f32 (needed for g0,g1); others folded into sums
            f32x4 a0 = *(const f32x4*)(pb + 0ull * (NB * CD));
            f32x4 c0 = *(const f32x4*)(pb + 0ull * (NB * CD) + 4);
            f32x4 a1 = *(const f32x4*)(pb + 1ull * (NB * CD));
            f32x4 c1 = *(const f32x4*)(pb + 1ull * (NB * CD) + 4);
            f32x4 a2 = *(const f32x4*)(pb + 2ull * (NB * CD));
            f32x4 c2 = *(const f32x4*)(pb + 2ull * (NB * CD) + 4);
            f32x4 a3 = *(const f32x4*)(pb + 3ull * (NB * CD));
            f32x4 c3 = *(const f32x4*)(pb + 3ull * (NB * CD) + 4);
            f32x4 a4 = *(const f32x4*)(pb + 4ull * (NB * CD));
            f32x4 c4 = *(const f32x4*)(pb + 4ull * (NB * CD) + 4);
            f32x4 a5 = *(const f32x4*)(pb + 5ull * (NB * CD));
            f32x4 c5 = *(const f32x4*)(pb + 5ull * (NB * CD) + 4);
            #pragma unroll
            for (int j = 0; j < 4; ++j) {
                x0[j] = a0[j]; x0[4 + j] = c0[j];
                x1[j] = a1[j]; x1[4 + j] = c1[j];
                S01[j] = a0[j] + a1[j]; S01[4 + j] = c0[j] + c1[j];
                S25[j] = a2[j] + a5[j]; S25[4 + j] = c2[j] + c5[j];
                S34[j] = a3[j] + a4[j]; S34[4 + j] = c3[j] + c4[j];
                xb[0][j] = f2bf(a0[j]); xb[0][4 + j] = f2bf(c0[j]);
                xb[1][j] = f2bf(a1[j]); xb[1][4 + j] = f2bf(c1[j]);
                xb[2][j] = f2bf(a2[j]); xb[2][4 + j] = f2bf(c2[j]);
                xb[3][j] = f2bf(a3[j]); xb[3][4 + j] = f2bf(c3[j]);
                xb[4][j] = f2bf(a4[j]); xb[4][4 + j] = f2bf(c4[j]);
                xb[5][j] = f2bf(a5[j]); xb[5][4 + j] = f2bf(c5[j]);
            }
        }
        // aggregates: g0=(T-x0)/5, g1=(T-x1)/5, g25=(S01+S34)/4, g34=(S01+S25)/4
        short8 g0b, g1b, g25b, g34b;
        #pragma unroll
        for (int j = 0; j < 8; ++j) {
            const float T = S01[j] + S25[j] + S34[j];
            g0b[j]  = f2bf((T - x0[j]) * 0.2f);
            g1b[j]  = f2bf((T - x1[j]) * 0.2f);
            g25b[j] = f2bf((S01[j] + S34[j]) * 0.25f);
            g34b[j] = f2bf((S01[j] + S25[j]) * 0.25f);
        }

        #pragma unroll
        for (int i = 0; i < 2; ++i) {
            const int o = obase + i * 16 + lo;
            short8 wa = *(const short8*)&Wb[o * KW + m * 32 + hi * 8];        // Wl half
            short8 wx = *(const short8*)&Wb[o * KW + 128 + m * 32 + hi * 8];  // Wr half
            // W as A-operand (D rows = out channels), data as B (D cols = rows)
            acc[0][i] = __builtin_amdgcn_mfma_f32_16x16x32_bf16(wa, g0b,  acc[0][i], 0, 0, 0);
            acc[1][i] = __builtin_amdgcn_mfma_f32_16x16x32_bf16(wa, g1b,  acc[1][i], 0, 0, 0);
            acc[2][i] = __builtin_amdgcn_mfma_f32_16x16x32_bf16(wa, g25b, acc[2][i], 0, 0, 0);
            acc[3][i] = __builtin_amdgcn_mfma_f32_16x16x32_bf16(wa, g34b, acc[3][i], 0, 0, 0);
            acc[4][i] = __builtin_amdgcn_mfma_f32_16x16x32_bf16(wa, g34b, acc[4][i], 0, 0, 0);
            acc[5][i] = __builtin_amdgcn_mfma_f32_16x16x32_bf16(wa, g25b, acc[5][i], 0, 0, 0);
            #pragma unroll
            for (int n = 0; n < NNODES; ++n)
                acc[n][i] = __builtin_amdgcn_mfma_f32_16x16x32_bf16(wx, xb[n], acc[n][i], 0, 0, 0);
        }
    }

    // epilogue: lane holds o = obase + i*16 + hi*4 + j (j=0..3 contiguous),
    // batch row = lo -> f32x4 stores. tanh-GELU (validated R3, absmax 0.031)
    #pragma unroll
    for (int n = 0; n < NNODES; ++n) {
        #pragma unroll
        for (int i = 0; i < 2; ++i) {
            f32x4 v = acc[n][i] + bias_v[i];
            f32x4 g;
            #pragma unroll
            for (int j = 0; j < 4; ++j) {
                const float s = v[j] * (0.7978845608f + 0.0356774081f * v[j] * v[j]);
                const float r = __builtin_amdgcn_exp2f(-2.885390082f * s);
                g[j] = v[j] * __builtin_amdgcn_rcpf(1.0f + r);
            }
            *(f32x4*)&out[row * OUTW + n * 256 + obase + i * 16 + hi * 4] = g;
        }
    }
}

extern "C" void kernel_launch(void* const* d_in, const int* in_sizes, int n_in,
                              void* d_out, int out_size, void* d_ws, size_t ws_size,
                              hipStream_t stream) {
    const float* x  = (const float*)d_in[0];
    const float* Wl = (const float*)d_in[1];
    const float* Wr = (const float*)d_in[2];
    const float* b  = (const float*)d_in[3];
    float* out = (float*)d_out;
    short* Wb = (short*)d_ws;   // 256*256 bf16 = 128 KB

    prep_w<<<dim3(32), dim3(256), 0, stream>>>(Wl, Wr, Wb);
    // (NB/16) row groups x 2 col-halves, XCD-pair swizzled
    sage_v4<<<dim3((NB / 16) * 2), dim3(256), 0, stream>>>(x, Wb, b, out);
}

// Round 5
// 96.747 us; speedup vs baseline: 1.7018x; 1.7018x over previous
//
#include <hip/hip_runtime.h>
#include <hip/hip_bf16.h>

#define NB 32768      // batch rows per node
#define CD 128        // input channels
#define NNODES 6
#define OUTW 1536     // 6*256 output cols
#define KW 256        // concat K per node GEMM

typedef __attribute__((ext_vector_type(8))) short short8;
typedef __attribute__((ext_vector_type(4))) float f32x4;

// hardware f32->bf16 (RNE)
static __device__ __forceinline__ short f2bf(float f) {
    union { __bf16 b; short s; } u;
    u.b = (__bf16)f;
    return u.s;
}

static __device__ __forceinline__ short8 pack8(f32x4 a, f32x4 b) {
    short8 p;
    #pragma unroll
    for (int j = 0; j < 4; ++j) { p[j] = f2bf(a[j]); p[4 + j] = f2bf(b[j]); }
    return p;
}

// ---- prologue: Wcat[o][k] bf16 in d_ws; k<128 -> Wl[o][k], else Wr[o][k-128]
__global__ void prep_w(const float* __restrict__ Wl, const float* __restrict__ Wr,
                       short* __restrict__ Wb) {
    const int i = (blockIdx.x * 256 + threadIdx.x) * 8;
    const int o = i >> 8;
    const int k = i & 255;
    const float* src = (k < 128) ? (Wl + o * CD + k) : (Wr + o * CD + (k - 128));
    *(short8*)(Wb + i) = pack8(*(const f32x4*)src, *(const f32x4*)(src + 4));
}

// LDS short-index with XOR swizzle: panel p (0..9), row r (0..15), k (0..127).
// byte ^= ((r&7)<<4)  ->  short_idx ^= ((r&7)<<3). Bijective within row;
// b128 reads land on (r&7)*4 bank offset -> 2-way max (free, m136).
#define LIDX(p, r, k) ((((p) << 11) + ((r) << 7) + (k)) ^ (((r) & 7) << 3))

// Block = 256 threads (4 waves) x 16 batch rows x ALL 1536 out cols.
// Prep: cooperative x load (redundancy 1x), 4 distinct aggregates, 10 bf16
// panels into LDS. Compute: wave w = 64-col strip of Wcat, swapped-operand
// MFMA (W=A, data=B; validated R4): D row = out channel, D col = batch row.
__global__ __launch_bounds__(256, 2)
void sage_v5(const float* __restrict__ x, const short* __restrict__ Wb,
             const float* __restrict__ bias, float* __restrict__ out) {
    __shared__ __align__(16) short A[10 * 16 * 128];   // 40 KB

    const int t = threadIdx.x;
    const size_t row0 = (size_t)blockIdx.x * 16;

    // ---------- prep phase: thread t -> row r = t>>4, 8-float chunk c = t&15
    {
        const int r = t >> 4;
        const int c = t & 15;
        const float* pb = x + (row0 + r) * CD + c * 8;
        f32x4 a0 = *(const f32x4*)(pb + 0ull * (NB * CD)), c0 = *(const f32x4*)(pb + 0ull * (NB * CD) + 4);
        f32x4 a1 = *(const f32x4*)(pb + 1ull * (NB * CD)), c1 = *(const f32x4*)(pb + 1ull * (NB * CD) + 4);
        f32x4 a2 = *(const f32x4*)(pb + 2ull * (NB * CD)), c2 = *(const f32x4*)(pb + 2ull * (NB * CD) + 4);
        f32x4 a3 = *(const f32x4*)(pb + 3ull * (NB * CD)), c3 = *(const f32x4*)(pb + 3ull * (NB * CD) + 4);
        f32x4 a4 = *(const f32x4*)(pb + 4ull * (NB * CD)), c4 = *(const f32x4*)(pb + 4ull * (NB * CD) + 4);
        f32x4 a5 = *(const f32x4*)(pb + 5ull * (NB * CD)), c5 = *(const f32x4*)(pb + 5ull * (NB * CD) + 4);

        f32x4 S01a = a0 + a1, S01c = c0 + c1;
        f32x4 S25a = a2 + a5, S25c = c2 + c5;
        f32x4 S34a = a3 + a4, S34c = c3 + c4;
        f32x4 Ta = S01a + S25a + S34a, Tc = S01c + S25c + S34c;

        const int k = c * 8;
        // agg panels: g0=(T-x0)/5, g1=(T-x1)/5, g25=(S01+S34)/4, g34=(S01+S25)/4
        *(short8*)&A[LIDX(0, r, k)] = pack8((Ta - a0) * 0.2f,  (Tc - c0) * 0.2f);
        *(short8*)&A[LIDX(1, r, k)] = pack8((Ta - a1) * 0.2f,  (Tc - c1) * 0.2f);
        *(short8*)&A[LIDX(2, r, k)] = pack8((S01a + S34a) * 0.25f, (S01c + S34c) * 0.25f);
        *(short8*)&A[LIDX(3, r, k)] = pack8((S01a + S25a) * 0.25f, (S01c + S25c) * 0.25f);
        *(short8*)&A[LIDX(4, r, k)] = pack8(a0, c0);
        *(short8*)&A[LIDX(5, r, k)] = pack8(a1, c1);
        *(short8*)&A[LIDX(6, r, k)] = pack8(a2, c2);
        *(short8*)&A[LIDX(7, r, k)] = pack8(a3, c3);
        *(short8*)&A[LIDX(8, r, k)] = pack8(a4, c4);
        *(short8*)&A[LIDX(9, r, k)] = pack8(a5, c5);
    }
    __syncthreads();

    // ---------- compute phase
    const int lane = t & 63;
    const int wv = t >> 6;
    const int lo = lane & 15;     // W row (out channel within tile) / D... batch col via B
    const int hi = lane >> 4;     // k-subchunk / D row-group
    const int obase = wv * 64;

    f32x4 acc[NNODES][4];
    #pragma unroll
    for (int n = 0; n < NNODES; ++n)
        #pragma unroll
        for (int i = 0; i < 4; ++i) acc[n][i] = (f32x4){0.f, 0.f, 0.f, 0.f};

    #pragma unroll
    for (int m = 0; m < 4; ++m) {
        const int kk = m * 32 + hi * 8;
        // data B-frags from LDS (broadcast to all 4 waves): col=lo(batch row),
        // k = m*32 + hi*8 + e  [R4-validated layout]
        short8 fg0 = *(const short8*)&A[LIDX(0, lo, kk)];
        short8 fg1 = *(const short8*)&A[LIDX(1, lo, kk)];
        short8 fg25 = *(const short8*)&A[LIDX(2, lo, kk)];
        short8 fg34 = *(const short8*)&A[LIDX(3, lo, kk)];
        short8 fx[NNODES];
        #pragma unroll
        for (int s = 0; s < NNODES; ++s)
            fx[s] = *(const short8*)&A[LIDX(4 + s, lo, kk)];

        #pragma unroll
        for (int i = 0; i < 4; ++i) {
            const int o = obase + i * 16 + lo;
            short8 wa = *(const short8*)&Wb[o * KW + kk];          // Wl half (k-step m)
            short8 wx = *(const short8*)&Wb[o * KW + 128 + kk];    // Wr half (k-step m+4)
            acc[0][i] = __builtin_amdgcn_mfma_f32_16x16x32_bf16(wa, fg0,  acc[0][i], 0, 0, 0);
            acc[1][i] = __builtin_amdgcn_mfma_f32_16x16x32_bf16(wa, fg1,  acc[1][i], 0, 0, 0);
            acc[2][i] = __builtin_amdgcn_mfma_f32_16x16x32_bf16(wa, fg25, acc[2][i], 0, 0, 0);
            acc[3][i] = __builtin_amdgcn_mfma_f32_16x16x32_bf16(wa, fg34, acc[3][i], 0, 0, 0);
            acc[4][i] = __builtin_amdgcn_mfma_f32_16x16x32_bf16(wa, fg34, acc[4][i], 0, 0, 0);
            acc[5][i] = __builtin_amdgcn_mfma_f32_16x16x32_bf16(wa, fg25, acc[5][i], 0, 0, 0);
            #pragma unroll
            for (int n = 0; n < NNODES; ++n)
                acc[n][i] = __builtin_amdgcn_mfma_f32_16x16x32_bf16(wx, fx[n], acc[n][i], 0, 0, 0);
        }
    }

    // ---------- epilogue: lane (lo,hi), o-tile i: o = obase+i*16+hi*4+{0..3},
    // batch row = lo  [R4-validated]. tanh-GELU (absmax 0.031 across rounds).
    #pragma unroll
    for (int n = 0; n < NNODES; ++n) {
        #pragma unroll
        for (int i = 0; i < 4; ++i) {
            f32x4 bv = *(const f32x4*)&bias[obase + i * 16 + hi * 4];
            f32x4 v = acc[n][i] + bv;
            f32x4 g;
            #pragma unroll
            for (int j = 0; j < 4; ++j) {
                const float s = v[j] * (0.7978845608f + 0.0356774081f * v[j] * v[j]);
                const float r = __builtin_amdgcn_exp2f(-2.885390082f * s);
                g[j] = v[j] * __builtin_amdgcn_rcpf(1.0f + r);
            }
            *(f32x4*)&out[(row0 + lo) * OUTW + n * 256 + obase + i * 16 + hi * 4] = g;
        }
    }
}

extern "C" void kernel_launch(void* const* d_in, const int* in_sizes, int n_in,
                              void* d_out, int out_size, void* d_ws, size_t ws_size,
                              hipStream_t stream) {
    const float* x  = (const float*)d_in[0];
    const float* Wl = (const float*)d_in[1];
    const float* Wr = (const float*)d_in[2];
    const float* b  = (const float*)d_in[3];
    float* out = (float*)d_out;
    short* Wb = (short*)d_ws;   // 256*256 bf16 = 128 KB

    prep_w<<<dim3(32), dim3(256), 0, stream>>>(Wl, Wr, Wb);
    sage_v5<<<dim3(NB / 16), dim3(256), 0, stream>>>(x, Wb, b, out);
}